// Round 8
// baseline (334.819 us; speedup 1.0000x reference)
//
#include <hip/hip_runtime.h>
#include <hip/hip_bf16.h>
#include <stdint.h>

typedef __bf16 bf16;
typedef __attribute__((ext_vector_type(8))) __bf16 bf16x8;
typedef __attribute__((ext_vector_type(4))) __bf16 bf16x4;
typedef __attribute__((ext_vector_type(4))) float f32x4;

// async global->LDS, 16B per lane. LDS dest is linear: wave base + lane*16.
#define GLD(g, l) __builtin_amdgcn_global_load_lds( \
    (const __attribute__((address_space(1))) void*)(g), \
    (__attribute__((address_space(3))) void*)(l), 16, 0, 0)

__device__ __forceinline__ f32x4 mfma16(bf16x8 a, bf16x8 b, f32x4 c) {
  return __builtin_amdgcn_mfma_f32_16x16x32_bf16(a, b, c, 0, 0, 0);
}
__device__ __forceinline__ float fexp2(float x) {
  return __builtin_amdgcn_exp2f(x);
}
__device__ __forceinline__ bf16x8 cvt8(const float4& a, const float4& b) {
  bf16x8 p;
  p[0] = (bf16)a.x; p[1] = (bf16)a.y; p[2] = (bf16)a.z; p[3] = (bf16)a.w;
  p[4] = (bf16)b.x; p[5] = (bf16)b.y; p[6] = (bf16)b.z; p[7] = (bf16)b.w;
  return p;
}

#define WAIT_BAR(cnt)                                            \
  asm volatile("s_waitcnt vmcnt(" #cnt ")" ::: "memory");        \
  __builtin_amdgcn_s_barrier();                                  \
  asm volatile("" ::: "memory")

// ---------------------------------------------------------------------------
// 128x128 compute step for gemm_a16_c32 (unchanged round-4 structure).
// LDS: A rows [128][32] | B rows [128][32] at +4096, swizzle cb'=cb^((row>>1)&3).
// ---------------------------------------------------------------------------
__device__ __forceinline__ void compute128(const bf16* buf, int wr, int wc,
                                           int lr, int quad,
                                           f32x4 (&acc)[4][4]) {
  bf16x8 af[4], bfr[4];
#pragma unroll
  for (int i = 0; i < 4; i++) {
    const int ra = wr + i * 16 + lr;
    const int rb = wc + i * 16 + lr;
    af[i]  = *(const bf16x8*)(buf + ra * 32 + ((quad ^ ((ra >> 1) & 3)) * 8));
    bfr[i] = *(const bf16x8*)(buf + 4096 + rb * 32 +
                              ((quad ^ ((rb >> 1) & 3)) * 8));
  }
  __builtin_amdgcn_s_setprio(1);
#pragma unroll
  for (int im = 0; im < 4; im++)
#pragma unroll
    for (int in = 0; in < 4; in++)
      acc[im][in] = mfma16(af[im], bfr[in], acc[im][in]);
  __builtin_amdgcn_s_setprio(0);
}

// ---------------------------------------------------------------------------
// ALL weight transposes in one dispatch. grid (32,32,4), block (32,8).
// ---------------------------------------------------------------------------
__global__ void wtransA(const float* __restrict__ Wq, const float* __restrict__ Wk,
                        const float* __restrict__ Wv, const float* __restrict__ Wo,
                        bf16* __restrict__ WT, bf16* __restrict__ WoT)
{
  __shared__ bf16 t[32][33];
  const int w = blockIdx.z;
  const int tx = threadIdx.x, ty = threadIdx.y;
  if (w < 3) {
    const float* W = (w == 0) ? Wq : (w == 1) ? Wk : Wv;
    const int h = blockIdx.x >> 1;
    const int c0 = (blockIdx.x & 1) * 32;
    const int r0 = blockIdx.y * 32;
    const float* s = W + (size_t)h * 65536;
    bf16* d = WT + (size_t)w * (1 << 20) + (size_t)h * 65536;
#pragma unroll
    for (int i = 0; i < 32; i += 8)
      t[ty + i][tx] = (bf16)s[(r0 + ty + i) * 64 + c0 + tx];
    __syncthreads();
#pragma unroll
    for (int i = 0; i < 32; i += 8)
      d[(c0 + ty + i) * 1024 + r0 + tx] = t[tx][ty + i];
  } else {
    const int c0 = blockIdx.x * 32, r0 = blockIdx.y * 32;
#pragma unroll
    for (int i = 0; i < 32; i += 8)
      t[ty + i][tx] = (bf16)Wo[(r0 + ty + i) * 1024 + c0 + tx];
    __syncthreads();
#pragma unroll
    for (int i = 0; i < 32; i += 8)
      WoT[(c0 + ty + i) * 1024 + r0 + tx] = t[tx][ty + i];
  }
}

// ---------------------------------------------------------------------------
// fp32 -> bf16 cast for q and k. grid (4096, 2). (round-4 verified)
// ---------------------------------------------------------------------------
__global__ __launch_bounds__(256) void cast2(const float* __restrict__ q,
                                             const float* __restrict__ k,
                                             bf16* __restrict__ qc,
                                             bf16* __restrict__ kc)
{
  const float* s = blockIdx.y ? k : q;
  bf16* d = blockIdx.y ? kc : qc;
  const size_t i = ((size_t)blockIdx.x * 256 + threadIdx.x) * 8;
  float4 a = *(const float4*)(s + i);
  float4 b = *(const float4*)(s + i + 4);
  *(bf16x8*)(d + i) = cvt8(a, b);
}

// ---------------------------------------------------------------------------
// ROUND-8 proj_qkv: 8-phase-family structure (T3+T4+T2+T5).
// BM=256, BN=128, 8 waves (2M x 4N), per-wave out 128x32. K split into 32
// HALF-TILES of 32 cols; each half = A[256][32] + B[128][32] bf16 = 24KB in a
// 5-buffer LDS ring (120KB) -> 3 halves of prefetch flight. Per half-pair:
//   vmcnt(6) [half h landed; h+1,h+2 in flight @3 GLD each] ; s_barrier ;
//   issue GLDs for half h+3 ; {ds_read af[8]+b0, setprio, 8 MFMA} x2 (b1).
// Never vmcnt(0) until the 2-pair tail peel. Swizzle cb'=cb^((row>>1)&3) on
// stage-source and read (verified conflict-free, round 2).
// Grid 768 1-D = 96 mt x 8 n, n=id&7==XCD (B panel 256KB L2-resident/XCD),
// 3 exactly-balanced seg-pure rounds. seg2: A fp32 reg-stage+cvt (B(h)
// anchored by cvt(h)'s f-wait, h=0 by explicit vmcnt(2) — round-2 discipline).
// ---------------------------------------------------------------------------
__global__ __launch_bounds__(512) void proj_qkv(
    const bf16* __restrict__ qc, const bf16* __restrict__ kc,
    const float* __restrict__ v, const bf16* __restrict__ WT,
    const float* __restrict__ bq, const float* __restrict__ bk,
    const float* __restrict__ bv, bf16* __restrict__ qh,
    bf16* __restrict__ kh, bf16* __restrict__ vt, float cscale)
{
  __shared__ bf16 S[5 * 12288];  // 120KB: 5 x (A 256x32 = 8192 el | B 128x32 = 4096 el)
  const int tid = threadIdx.x;
  const int wave = tid >> 6, lane = tid & 63;
  const int lr = lane & 15, quad = lane >> 4;
  const int id = blockIdx.x;
  const int n0 = (id & 7) * 128;       // n == XCD
  const int mt = id >> 3;
  const int seg = mt >> 5;
  const int m0 = (mt & 31) * 256;
  const int wm = wave >> 2, wn = wave & 3;
  const int wr = wm * 128;             // wave row base (A rows)
  const int wc = wn * 32;              // wave col base (B rows)

  const float* bias = (seg == 0) ? bq : (seg == 1) ? bk : bv;
  const bf16* Bt = WT + (size_t)seg * (1 << 20);

  f32x4 acc[8][2];
#pragma unroll
  for (int i = 0; i < 8; i++)
#pragma unroll
    for (int j = 0; j < 2; j++)
#pragma unroll
      for (int e = 0; e < 4; e++) acc[i][j][e] = 0.f;

  // staging maps: row = tid>>2, slot = tid&3, swizzled source col-block
  const int sko = (((tid & 3) ^ ((tid >> 3) & 3))) * 8;
  const int srow = tid >> 2;                       // 0..127
  const bf16* bPtr = Bt + (size_t)(n0 + srow) * 1024 + sko;

  // per-half compute (two sub-phases: in=0, in=1)
  auto pair_compute = [&](const bf16* buf) {
    bf16x8 af[8];
#pragma unroll
    for (int i = 0; i < 8; i++) {
      const int ra = wr + i * 16 + lr;
      af[i] = *(const bf16x8*)(buf + ra * 32 + ((quad ^ ((ra >> 1) & 3)) * 8));
    }
    const int rb0 = wc + lr;
    bf16x8 b0 = *(const bf16x8*)(buf + 8192 + rb0 * 32 +
                                 ((quad ^ ((rb0 >> 1) & 3)) * 8));
    __builtin_amdgcn_s_setprio(1);
#pragma unroll
    for (int i = 0; i < 8; i++) acc[i][0] = mfma16(af[i], b0, acc[i][0]);
    __builtin_amdgcn_s_setprio(0);
    const int rb1 = wc + 16 + lr;
    bf16x8 b1 = *(const bf16x8*)(buf + 8192 + rb1 * 32 +
                                 ((quad ^ ((rb1 >> 1) & 3)) * 8));
    __builtin_amdgcn_s_setprio(1);
#pragma unroll
    for (int i = 0; i < 8; i++) acc[i][1] = mfma16(af[i], b1, acc[i][1]);
    __builtin_amdgcn_s_setprio(0);
  };

  if (seg < 2) {
    const bf16* Ab = (seg == 1) ? kc : qc;
    const bf16* aPtr  = Ab + (size_t)(m0 + srow) * 1024 + sko;   // rows 0-127
    const bf16* aPtr2 = aPtr + (size_t)128 * 1024;               // rows 128-255
    // prologue: halves 0,1,2 in flight (3 GLDs each)
#pragma unroll
    for (int t = 0; t < 3; ++t) {
      bf16* nb = S + t * 12288;
      GLD(aPtr  + t * 32, nb + tid * 8);
      GLD(aPtr2 + t * 32, nb + 4096 + tid * 8);
      GLD(bPtr  + t * 32, nb + 8192 + tid * 8);
    }
    for (int h = 0; h < 30; ++h) {
      // vmcnt(6): half h landed (h+1,h+2 = 6 outstanding); barrier: all waves
      // finished reading half h-1 -> buf (h+3)%5 (last read at pair h-2) free.
      WAIT_BAR(6);
      if (h < 29) {
        const int k0 = (h + 3) * 32;
        bf16* nb = S + ((h + 3) % 5) * 12288;
        GLD(aPtr  + k0, nb + tid * 8);
        GLD(aPtr2 + k0, nb + 4096 + tid * 8);
        GLD(bPtr  + k0, nb + 8192 + tid * 8);
      }
      pair_compute(S + (h % 5) * 12288);
    }
    // tail: outstanding 6 / 3 -> waits 3 / 0
    WAIT_BAR(3);
    pair_compute(S + (30 % 5) * 12288);
    WAIT_BAR(0);
    pair_compute(S + (31 % 5) * 12288);
  } else {
    // A fp32 from v: row = tid>>1 (0..255), two col-blocks at acb=(tid&1)*2
    const int ar = tid >> 1, acb = (tid & 1) * 2;
    const int asw = (ar >> 1) & 3;
    const float* vPtr = v + (size_t)(m0 + ar) * 1024 + acb * 8;
    float4 f[4];
#pragma unroll
    for (int j = 0; j < 4; j++) f[j] = *(const float4*)(vPtr + j * 4);
    {  // A(0) cvt+store into buf0 (no readers yet)
      *(bf16x8*)(S + ar * 32 + ((acb ^ asw) * 8))       = cvt8(f[0], f[1]);
      *(bf16x8*)(S + ar * 32 + (((acb + 1) ^ asw) * 8)) = cvt8(f[2], f[3]);
    }
    // B halves 0,1,2 (1 GLD each)
    GLD(bPtr,      S + 8192 + tid * 8);
    GLD(bPtr + 32, S + 12288 + 8192 + tid * 8);
    GLD(bPtr + 64, S + 24576 + 8192 + tid * 8);
    // drain B(0): outstanding = B0,B1,B2 = 3 (f(0) drained by cvt dep)
    asm volatile("s_waitcnt vmcnt(2)" ::: "memory");
    for (int h = 0; h < 32; ++h) {
      // lgkmcnt(0): this wave's A(h) ds_writes landed (end of pair h-1);
      // barrier publishes them + B(h) (h=0: explicit vmcnt above; h>=1:
      // cvt(h)'s data-dep f(h)-wait at end of pair h-1 drains B(h) too).
      asm volatile("s_waitcnt lgkmcnt(0)" ::: "memory");
      __builtin_amdgcn_sched_barrier(0);
      __builtin_amdgcn_s_barrier();
      asm volatile("" ::: "memory");
      const bool moreA = (h + 1 < 32);
      if (moreA) {  // f(h+1) issued FIRST (before B(h+3)) so cvt(h+1)'s wait
                    // does not drain B(h+3)
        const int k0 = (h + 1) * 32;
#pragma unroll
        for (int j = 0; j < 4; j++) f[j] = *(const float4*)(vPtr + k0 + j * 4);
      }
      if (h + 3 < 32) {
        const int k0 = (h + 3) * 32;
        GLD(bPtr + k0, S + ((h + 3) % 5) * 12288 + 8192 + tid * 8);
      }
      pair_compute(S + (h % 5) * 12288);
      if (moreA) {  // cvt (f landed during compute) + store into buf (h+1)%5
        bf16* nb = S + ((h + 1) % 5) * 12288;
        *(bf16x8*)(nb + ar * 32 + ((acb ^ asw) * 8))       = cvt8(f[0], f[1]);
        *(bf16x8*)(nb + ar * 32 + (((acb + 1) ^ asw) * 8)) = cvt8(f[2], f[3]);
      }
    }
  }

  const int qd = quad * 4;
  float bv2[2];
#pragma unroll
  for (int in = 0; in < 2; in++) bv2[in] = bias[n0 + wc + in * 16 + lr];

  if (seg < 2) {
    bf16* C = (seg == 0) ? qh : kh;
    const float cmul = (seg == 0) ? cscale : 1.0f;
#pragma unroll
    for (int im = 0; im < 8; im++) {
      const int row = m0 + wr + im * 16 + qd;
#pragma unroll
      for (int in = 0; in < 2; in++) {
        const int col = n0 + wc + in * 16 + lr;
#pragma unroll
        for (int i = 0; i < 4; i++)
          C[(size_t)(row + i) * 1024 + col] = (bf16)((acc[im][in][i] + bv2[in]) * cmul);
      }
    }
  } else {
#pragma unroll
    for (int im = 0; im < 8; im++) {
      const int row = m0 + wr + im * 16 + qd;
      const int b = row >> 10, sin = row & 1023;
#pragma unroll
      for (int in = 0; in < 2; in++) {
        const int col = n0 + wc + in * 16 + lr;
        const int h = col >> 6, e = col & 63;
        bf16x4 pk;
#pragma unroll
        for (int i = 0; i < 4; i++) pk[i] = (bf16)(acc[im][in][i] + bv2[in]);
        *(bf16x4*)(vt + (size_t)(b * 16 + h) * 65536 + e * 1024 + sin) = pk;
      }
    }
  }
}

// ---------------------------------------------------------------------------
// Final GEMM: out[8192,1024](fp32) = A(bf16) @ WoT^T + bo. (round-4 verified)
// 3-ring depth-2 counted-vmcnt + swizzled staging. Grid (8 n-fast, 64 m).
// ---------------------------------------------------------------------------
__global__ __launch_bounds__(256) void gemm_a16_c32(
    const bf16* __restrict__ A, const bf16* __restrict__ Bt,
    const float* __restrict__ bias, float* __restrict__ C)
{
  __shared__ bf16 S[24576];
  const int tid = threadIdx.x;
  const int wave = tid >> 6, lane = tid & 63;
  const int lr = lane & 15, quad = lane >> 4;
  const int n0 = blockIdx.x * 128;
  const int m0 = blockIdx.y * 128;
  const int wr = (wave >> 1) * 64, wc = (wave & 1) * 64;

  f32x4 acc[4][4];
#pragma unroll
  for (int i = 0; i < 4; i++)
#pragma unroll
    for (int j = 0; j < 4; j++)
#pragma unroll
      for (int e = 0; e < 4; e++) acc[i][j][e] = 0.f;

  const int srow = tid >> 2;
  const int sko = ((tid & 3) ^ ((srow >> 1) & 3)) * 8;
  const bf16* aPtr = A + (size_t)(m0 + srow) * 1024 + sko;
  const bf16* bPtr = Bt + (size_t)(n0 + srow) * 1024 + sko;

  int i0 = 0, i1 = 1, i2 = 2;
#pragma unroll
  for (int t = 0; t < 2; ++t) {
    bf16* nb = S + t * 8192;
    GLD(aPtr + t * 32,             nb + tid * 8);
    GLD(aPtr + 64 * 1024 + t * 32, nb + 2048 + tid * 8);
    GLD(bPtr + t * 32,             nb + 4096 + tid * 8);
    GLD(bPtr + 64 * 1024 + t * 32, nb + 6144 + tid * 8);
  }
  for (int it = 0; it < 30; ++it) {
    WAIT_BAR(4);
    const int k0 = (it + 2) * 32;
    bf16* nb = S + i2 * 8192;
    GLD(aPtr + k0,             nb + tid * 8);
    GLD(aPtr + 64 * 1024 + k0, nb + 2048 + tid * 8);
    GLD(bPtr + k0,             nb + 4096 + tid * 8);
    GLD(bPtr + 64 * 1024 + k0, nb + 6144 + tid * 8);
    compute128(S + i0 * 8192, wr, wc, lr, quad, acc);
    const int t = i0; i0 = i1; i1 = i2; i2 = t;
  }
  WAIT_BAR(4);
  compute128(S + i0 * 8192, wr, wc, lr, quad, acc);
  WAIT_BAR(0);
  compute128(S + i1 * 8192, wr, wc, lr, quad, acc);

  const int qd = quad * 4;
  float bv4[4];
#pragma unroll
  for (int in = 0; in < 4; in++) bv4[in] = bias[n0 + wc + in * 16 + lr];
#pragma unroll
  for (int im = 0; im < 4; im++) {
    const int row = m0 + wr + im * 16 + qd;
#pragma unroll
    for (int in = 0; in < 4; in++) {
      const int col = n0 + wc + in * 16 + lr;
#pragma unroll
      for (int i = 0; i < 4; i++)
        C[(size_t)(row + i) * 1024 + col] = acc[im][in][i] + bv4[in];
    }
  }
}

// ---------------------------------------------------------------------------
// Flash attention per (b,h). (round-5/7 verified: q-fast grid + setprio)
// ---------------------------------------------------------------------------
__global__ __launch_bounds__(256) void attn_k(
    const bf16* Q, const bf16* __restrict__ Kh,
    const bf16* __restrict__ Vt, bf16* O)
{
  __shared__ bf16 sK[64 * 72];
  __shared__ bf16 sV[64 * 72];
  __shared__ bf16 sP[128 * 72];
  const int q0 = blockIdx.x * 128, h = blockIdx.y, b = blockIdx.z;
  const int tid = threadIdx.x, wave = tid >> 6, lane = tid & 63;
  const int lr = lane & 15, quad = lane >> 4, kq = quad * 8;
  const int wq = wave * 32;

  const bf16* Qb = Q + (size_t)(b * 1024 + q0) * 1024 + h * 64;
  const bf16* Kb = Kh + (size_t)(b * 1024) * 1024 + h * 64;
  const bf16* Vb = Vt + (size_t)(b * 16 + h) * 65536;

  bf16x8 qf[2][2];
#pragma unroll
  for (int rg = 0; rg < 2; rg++)
#pragma unroll
    for (int ks = 0; ks < 2; ks++)
      qf[rg][ks] = *(const bf16x8*)(Qb + (wq + rg * 16 + lr) * 1024 + ks * 32 + kq);

  f32x4 o[2][4];
  float rsum[2][4];
#pragma unroll
  for (int rg = 0; rg < 2; rg++) {
#pragma unroll
    for (int et = 0; et < 4; et++)
#pragma unroll
      for (int e = 0; e < 4; e++) o[rg][et][e] = 0.f;
#pragma unroll
    for (int i = 0; i < 4; i++) rsum[rg][i] = 0.f;
  }

  const int r = tid >> 3;
  const int c = (tid & 7) * 8;

  bf16x8 k1 = *(const bf16x8*)(Kb + (size_t)r * 1024 + c);
  bf16x8 k2 = *(const bf16x8*)(Kb + (size_t)(32 + r) * 1024 + c);
  bf16x8 v1 = *(const bf16x8*)(Vb + (size_t)r * 1024 + c);
  bf16x8 v2 = *(const bf16x8*)(Vb + (size_t)(32 + r) * 1024 + c);

  for (int kv0 = 0; kv0 < 1024; kv0 += 64) {
    __syncthreads();
    *(bf16x8*)(sK + r * 72 + c) = k1;
    *(bf16x8*)(sK + (32 + r) * 72 + c) = k2;
    *(bf16x8*)(sV + r * 72 + c) = v1;
    *(bf16x8*)(sV + (32 + r) * 72 + c) = v2;
    __syncthreads();
    if (kv0 + 64 < 1024) {
      k1 = *(const bf16x8*)(Kb + (size_t)(kv0 + 64 + r) * 1024 + c);
      k2 = *(const bf16x8*)(Kb + (size_t)(kv0 + 96 + r) * 1024 + c);
      v1 = *(const bf16x8*)(Vb + (size_t)r * 1024 + kv0 + 64 + c);
      v2 = *(const bf16x8*)(Vb + (size_t)(32 + r) * 1024 + kv0 + 64 + c);
    }

    f32x4 sc[2][4];
    __builtin_amdgcn_s_setprio(1);
#pragma unroll
    for (int nt = 0; nt < 4; nt++) {
      bf16x8 kf0 = *(const bf16x8*)(sK + (nt * 16 + lr) * 72 + kq);
      bf16x8 kf1 = *(const bf16x8*)(sK + (nt * 16 + lr) * 72 + 32 + kq);
#pragma unroll
      for (int rg = 0; rg < 2; rg++) {
        f32x4 z;
#pragma unroll
        for (int e = 0; e < 4; e++) z[e] = 0.f;
        z = mfma16(qf[rg][0], kf0, z);
        z = mfma16(qf[rg][1], kf1, z);
        sc[rg][nt] = z;
      }
    }
    __builtin_amdgcn_s_setprio(0);

#pragma unroll
    for (int rg = 0; rg < 2; rg++)
#pragma unroll
      for (int i = 0; i < 4; i++) {
        float p0 = fexp2(sc[rg][0][i]);
        float p1 = fexp2(sc[rg][1][i]);
        float p2 = fexp2(sc[rg][2][i]);
        float p3 = fexp2(sc[rg][3][i]);
        rsum[rg][i] += (p0 + p1) + (p2 + p3);
        const int prow = (wq + rg * 16 + quad * 4 + i) * 72;
        sP[prow + 0 * 16 + lr] = (bf16)p0;
        sP[prow + 1 * 16 + lr] = (bf16)p1;
        sP[prow + 2 * 16 + lr] = (bf16)p2;
        sP[prow + 3 * 16 + lr] = (bf16)p3;
      }
    __syncthreads();

    __builtin_amdgcn_s_setprio(1);
#pragma unroll
    for (int et = 0; et < 4; et++) {
      bf16x8 vf0 = *(const bf16x8*)(sV + (et * 16 + lr) * 72 + kq);
      bf16x8 vf1 = *(const bf16x8*)(sV + (et * 16 + lr) * 72 + 32 + kq);
#pragma unroll
      for (int rg = 0; rg < 2; rg++) {
        bf16x8 pa = *(const bf16x8*)(sP + (wq + rg * 16 + lr) * 72 + kq);
        bf16x8 pb = *(const bf16x8*)(sP + (wq + rg * 16 + lr) * 72 + 32 + kq);
        o[rg][et] = mfma16(pa, vf0, o[rg][et]);
        o[rg][et] = mfma16(pb, vf1, o[rg][et]);
      }
    }
    __builtin_amdgcn_s_setprio(0);
  }

#pragma unroll
  for (int rg = 0; rg < 2; rg++)
#pragma unroll
    for (int i = 0; i < 4; i++) {
      float rs = rsum[rg][i];
#pragma unroll
      for (int off = 1; off < 16; off <<= 1)
        rs += __shfl_xor(rs, off, 64);
      rsum[rg][i] = 1.f / rs;
    }

  bf16* Ob = O + (size_t)(b * 1024 + q0) * 1024 + h * 64;
#pragma unroll
  for (int rg = 0; rg < 2; rg++)
#pragma unroll
    for (int i = 0; i < 4; i++) {
      const int row = wq + rg * 16 + quad * 4 + i;
#pragma unroll
      for (int et = 0; et < 4; et++)
        Ob[row * 1024 + et * 16 + lr] = (bf16)(o[rg][et][i] * rsum[rg][i]);
    }
}

// ---------------------------------------------------------------------------
extern "C" void kernel_launch(void* const* d_in, const int* in_sizes, int n_in,
                              void* d_out, int out_size, void* d_ws, size_t ws_size,
                              hipStream_t stream)
{
  const float* q  = (const float*)d_in[0];
  const float* k  = (const float*)d_in[1];
  const float* v  = (const float*)d_in[2];
  const float* Wq = (const float*)d_in[3];
  const float* bq = (const float*)d_in[4];
  const float* Wk = (const float*)d_in[5];
  const float* bk = (const float*)d_in[6];
  const float* Wv = (const float*)d_in[7];
  const float* bv = (const float*)d_in[8];
  const float* Wo = (const float*)d_in[9];
  const float* bo = (const float*)d_in[10];
  float* out = (float*)d_out;
  bf16* ws = (bf16*)d_ws;

  const int MB = 1 << 20;
  bf16* WT  = ws;               // [3][1024][1024]
  bf16* qh  = ws + 3 * MB;      // [8192][1024]; attn writes O in-place here
  bf16* kh  = ws + 11 * MB;     // [8192][1024]
  bf16* vt  = ws + 19 * MB;     // [B*H][64 e][1024 s]
  bf16* WoT = ws + 27 * MB;     // [1024][1024]  (ws total 56 MB)
  bf16* qc  = (bf16*)d_out;             // d_out as scratch (dead before final GEMM)
  bf16* kc  = (bf16*)d_out + 8 * MB;

  const float cscale = 0.1803368801111601f;  // (1/8)*log2(e), folded into qh

  dim3 tb(32, 8);
  wtransA<<<dim3(32, 32, 4), tb, 0, stream>>>(Wq, Wk, Wv, Wo, WT, WoT);
  cast2<<<dim3(4096, 2), 256, 0, stream>>>(q, k, qc, kc);

  proj_qkv<<<dim3(768), 512, 0, stream>>>(qc, kc, v, WT, bq, bk, bv,
                                          qh, kh, vt, cscale);

  attn_k<<<dim3(8, 16, 8), 256, 0, stream>>>(qh, kh, vt, qh);

  gemm_a16_c32<<<dim3(8, 64), 256, 0, stream>>>(qh, WoT, bo, out);
}

// Round 9
// 325.316 us; speedup vs baseline: 1.0292x; 1.0292x over previous
//
#include <hip/hip_runtime.h>
#include <hip/hip_bf16.h>
#include <stdint.h>

typedef __bf16 bf16;
typedef __attribute__((ext_vector_type(8))) __bf16 bf16x8;
typedef __attribute__((ext_vector_type(4))) __bf16 bf16x4;
typedef __attribute__((ext_vector_type(4))) float f32x4;

// async global->LDS, 16B per lane. LDS dest is linear: wave base + lane*16.
#define GLD(g, l) __builtin_amdgcn_global_load_lds( \
    (const __attribute__((address_space(1))) void*)(g), \
    (__attribute__((address_space(3))) void*)(l), 16, 0, 0)

__device__ __forceinline__ f32x4 mfma16(bf16x8 a, bf16x8 b, f32x4 c) {
  return __builtin_amdgcn_mfma_f32_16x16x32_bf16(a, b, c, 0, 0, 0);
}
__device__ __forceinline__ float fexp2(float x) {
  return __builtin_amdgcn_exp2f(x);
}
__device__ __forceinline__ bf16x8 cvt8(const float4& a, const float4& b) {
  bf16x8 p;
  p[0] = (bf16)a.x; p[1] = (bf16)a.y; p[2] = (bf16)a.z; p[3] = (bf16)a.w;
  p[4] = (bf16)b.x; p[5] = (bf16)b.y; p[6] = (bf16)b.z; p[7] = (bf16)b.w;
  return p;
}

// ---------------------------------------------------------------------------
// Shared 128x128 MFMA compute step on one (A|B) LDS buffer.
// LDS: A rows [128][32] | B rows [128][32] at +4096, swizzle cb'=cb^((row>>1)&3).
// Conflict-free b128 reads (verified round 2: SQ_LDS_BANK_CONFLICT 7.34M -> 0).
// ---------------------------------------------------------------------------
__device__ __forceinline__ void compute128(const bf16* buf, int wr, int wc,
                                           int lr, int quad,
                                           f32x4 (&acc)[4][4]) {
  bf16x8 af[4], bfr[4];
#pragma unroll
  for (int i = 0; i < 4; i++) {
    const int ra = wr + i * 16 + lr;
    const int rb = wc + i * 16 + lr;
    af[i]  = *(const bf16x8*)(buf + ra * 32 + ((quad ^ ((ra >> 1) & 3)) * 8));
    bfr[i] = *(const bf16x8*)(buf + 4096 + rb * 32 +
                              ((quad ^ ((rb >> 1) & 3)) * 8));
  }
  __builtin_amdgcn_s_setprio(1);
#pragma unroll
  for (int im = 0; im < 4; im++)
#pragma unroll
    for (int in = 0; in < 4; in++)
      acc[im][in] = mfma16(af[im], bfr[in], acc[im][in]);
  __builtin_amdgcn_s_setprio(0);
}

#define WAIT_BAR(cnt)                                            \
  asm volatile("s_waitcnt vmcnt(" #cnt ")" ::: "memory");        \
  __builtin_amdgcn_s_barrier();                                  \
  asm volatile("" ::: "memory")

// ---------------------------------------------------------------------------
// ALL weight transposes + q/k fp32->bf16 cast in ONE dispatch.
// z<3: W{q,k,v}[h][1024][64] -> WT[z][(h*64+e)][d]. z==3: Wo -> WoT[n][k].
// z in [4,12): cast chunks (one fewer launch gap vs separate cast2).
// grid (32,32,12), block (32,8).
// ---------------------------------------------------------------------------
__global__ void wtransA(const float* __restrict__ Wq, const float* __restrict__ Wk,
                        const float* __restrict__ Wv, const float* __restrict__ Wo,
                        bf16* __restrict__ WT, bf16* __restrict__ WoT,
                        const float* __restrict__ q, const float* __restrict__ k,
                        bf16* __restrict__ qc, bf16* __restrict__ kc)
{
  __shared__ bf16 t[32][33];
  const int w = blockIdx.z;
  const int tx = threadIdx.x, ty = threadIdx.y;
  if (w < 3) {
    const float* W = (w == 0) ? Wq : (w == 1) ? Wk : Wv;
    const int h = blockIdx.x >> 1;
    const int c0 = (blockIdx.x & 1) * 32;
    const int r0 = blockIdx.y * 32;
    const float* s = W + (size_t)h * 65536;
    bf16* d = WT + (size_t)w * (1 << 20) + (size_t)h * 65536;
#pragma unroll
    for (int i = 0; i < 32; i += 8)
      t[ty + i][tx] = (bf16)s[(r0 + ty + i) * 64 + c0 + tx];
    __syncthreads();
#pragma unroll
    for (int i = 0; i < 32; i += 8)
      d[(c0 + ty + i) * 1024 + r0 + tx] = t[tx][ty + i];
  } else if (w == 3) {
    const int c0 = blockIdx.x * 32, r0 = blockIdx.y * 32;
#pragma unroll
    for (int i = 0; i < 32; i += 8)
      t[ty + i][tx] = (bf16)Wo[(r0 + ty + i) * 1024 + c0 + tx];
    __syncthreads();
#pragma unroll
    for (int i = 0; i < 32; i += 8)
      WoT[(c0 + ty + i) * 1024 + r0 + tx] = t[tx][ty + i];
  } else {
    // cast: lb in [0,8192); lb<4096 -> q chunk, else k chunk. 2048 el/block.
    const int tid = ty * 32 + tx;
    const int lb = (w - 4) * 1024 + blockIdx.y * 32 + blockIdx.x;
    const float* s = (lb < 4096) ? q : k;
    bf16* d = (lb < 4096) ? qc : kc;
    const size_t base = ((size_t)(lb & 4095) * 256 + tid) * 8;
    float4 a = *(const float4*)(s + base);
    float4 b = *(const float4*)(s + base + 4);
    *(bf16x8*)(d + base) = cvt8(a, b);
  }
}

// ---------------------------------------------------------------------------
// Fused QKV projection, stacked-M (seg = q/k/v). 128x128 tile, BK=32,
// 3-buffer LDS ring (48KB -> 3 blocks/CU), depth-2 counted prefetch:
// WAIT_BAR vmcnt(4), never 0 in main loop. ROUND-7 VERIFIED: 103us,
// MfmaUtil 20%, conflicts 0. (Round-8's 256x128 1-block/CU port regressed
// to 114us — coarse phase-split + TLP loss; reverted.)
// Grid (8 n-fast, 192 mt): n == id%8 == XCD -> per-XCD L2-resident B panel;
// A panels shared by 8 XCDs via L3. Seg-pure rounds -> balanced.
// ---------------------------------------------------------------------------
__global__ __launch_bounds__(256) void proj_qkv(
    const bf16* __restrict__ qc, const bf16* __restrict__ kc,
    const float* __restrict__ v, const bf16* __restrict__ WT,
    const float* __restrict__ bq, const float* __restrict__ bk,
    const float* __restrict__ bv, bf16* __restrict__ qh,
    bf16* __restrict__ kh, bf16* __restrict__ vt, float cscale)
{
  __shared__ bf16 S[24576];  // 48KB: 3 bufs x (A 4096 el | B 4096 el)
  const int tid = threadIdx.x;
  const int wave = tid >> 6, lane = tid & 63;
  const int lr = lane & 15, quad = lane >> 4;
  const int n0 = blockIdx.x * 128;   // n == XCD (id%8 round-robin)
  const int mt = blockIdx.y;
  const int mseg = mt * 128;
  const int seg = mseg >> 13;
  const int m0 = mseg & 8191;
  const int wr = (wave >> 1) * 64, wc = (wave & 1) * 64;

  const float* bias = (seg == 0) ? bq : (seg == 1) ? bk : bv;
  const bf16* Bt = WT + (size_t)seg * (1 << 20);

  f32x4 acc[4][4];
#pragma unroll
  for (int i = 0; i < 4; i++)
#pragma unroll
    for (int j = 0; j < 4; j++)
#pragma unroll
      for (int e = 0; e < 4; e++) acc[i][j][e] = 0.f;

  const int srow = tid >> 2;
  const int sko = ((tid & 3) ^ ((srow >> 1) & 3)) * 8;
  const bf16* bPtr = Bt + (size_t)(n0 + srow) * 1024 + sko;

  int i0 = 0, i1 = 1, i2 = 2;

  if (seg < 2) {
    const bf16* Ab = (seg == 1) ? kc : qc;
    const bf16* aPtr = Ab + (size_t)(m0 + srow) * 1024 + sko;
#pragma unroll
    for (int t = 0; t < 2; ++t) {
      bf16* nb = S + t * 8192;
      GLD(aPtr + t * 32,             nb + tid * 8);
      GLD(aPtr + 64 * 1024 + t * 32, nb + 2048 + tid * 8);
      GLD(bPtr + t * 32,             nb + 4096 + tid * 8);
      GLD(bPtr + 64 * 1024 + t * 32, nb + 6144 + tid * 8);
    }
    for (int it = 0; it < 30; ++it) {
      WAIT_BAR(4);
      const int k0 = (it + 2) * 32;
      bf16* nb = S + i2 * 8192;
      GLD(aPtr + k0,             nb + tid * 8);
      GLD(aPtr + 64 * 1024 + k0, nb + 2048 + tid * 8);
      GLD(bPtr + k0,             nb + 4096 + tid * 8);
      GLD(bPtr + 64 * 1024 + k0, nb + 6144 + tid * 8);
      compute128(S + i0 * 8192, wr, wc, lr, quad, acc);
      const int t = i0; i0 = i1; i1 = i2; i2 = t;
    }
    WAIT_BAR(4);
    compute128(S + i0 * 8192, wr, wc, lr, quad, acc);
    WAIT_BAR(0);
    compute128(S + i1 * 8192, wr, wc, lr, quad, acc);
  } else {
    const int ar = tid >> 1, acb = (tid & 1) * 2;
    const int asw = (ar >> 1) & 3;
    const float* vPtr = v + (size_t)(m0 + ar) * 1024 + acb * 8;
    float4 f[4];
#pragma unroll
    for (int j = 0; j < 4; j++) f[j] = *(const float4*)(vPtr + j * 4);
    {
      *(bf16x8*)(S + ar * 32 + ((acb ^ asw) * 8))       = cvt8(f[0], f[1]);
      *(bf16x8*)(S + ar * 32 + (((acb + 1) ^ asw) * 8)) = cvt8(f[2], f[3]);
    }
    GLD(bPtr,                  S + 4096 + tid * 8);
    GLD(bPtr + 64 * 1024,      S + 6144 + tid * 8);
    GLD(bPtr + 32,             S + 8192 + 4096 + tid * 8);
    GLD(bPtr + 64 * 1024 + 32, S + 8192 + 6144 + tid * 8);
    asm volatile("s_waitcnt vmcnt(2)" ::: "memory");
    for (int it = 0; it < 32; ++it) {
      asm volatile("s_waitcnt lgkmcnt(0)" ::: "memory");
      __builtin_amdgcn_sched_barrier(0);
      __builtin_amdgcn_s_barrier();
      asm volatile("" ::: "memory");
      const bool moreA = (it + 1 < 32);
      if (moreA) {
        const int k0 = (it + 1) * 32;
#pragma unroll
        for (int j = 0; j < 4; j++) f[j] = *(const float4*)(vPtr + k0 + j * 4);
      }
      if (it + 2 < 32) {
        const int k0 = (it + 2) * 32;
        bf16* nb = S + i2 * 8192;
        GLD(bPtr + k0,             nb + 4096 + tid * 8);
        GLD(bPtr + 64 * 1024 + k0, nb + 6144 + tid * 8);
      }
      compute128(S + i0 * 8192, wr, wc, lr, quad, acc);
      if (moreA) {
        bf16* nb = S + i1 * 8192;
        *(bf16x8*)(nb + ar * 32 + ((acb ^ asw) * 8))       = cvt8(f[0], f[1]);
        *(bf16x8*)(nb + ar * 32 + (((acb + 1) ^ asw) * 8)) = cvt8(f[2], f[3]);
      }
      const int t = i0; i0 = i1; i1 = i2; i2 = t;
    }
  }

  const int qd = quad * 4;
  float bv4[4];
#pragma unroll
  for (int in = 0; in < 4; in++) bv4[in] = bias[n0 + wc + in * 16 + lr];

  if (seg < 2) {
    bf16* C = (seg == 0) ? qh : kh;
    const float cmul = (seg == 0) ? cscale : 1.0f;
#pragma unroll
    for (int im = 0; im < 4; im++) {
      const int row = m0 + wr + im * 16 + qd;
#pragma unroll
      for (int in = 0; in < 4; in++) {
        const int col = n0 + wc + in * 16 + lr;
#pragma unroll
        for (int i = 0; i < 4; i++)
          C[(size_t)(row + i) * 1024 + col] = (bf16)((acc[im][in][i] + bv4[in]) * cmul);
      }
    }
  } else {
#pragma unroll
    for (int im = 0; im < 4; im++) {
      const int row = m0 + wr + im * 16 + qd;
      const int b = row >> 10, sin = row & 1023;
#pragma unroll
      for (int in = 0; in < 4; in++) {
        const int col = n0 + wc + in * 16 + lr;
        const int h = col >> 6, e = col & 63;
        bf16x4 pk;
#pragma unroll
        for (int i = 0; i < 4; i++) pk[i] = (bf16)(acc[im][in][i] + bv4[in]);
        *(bf16x4*)(vt + (size_t)(b * 16 + h) * 65536 + e * 1024 + sin) = pk;
      }
    }
  }
}

// ---------------------------------------------------------------------------
// Final GEMM: out[8192,1024](fp32) = A(bf16) @ WoT^T + bo. (round-4 verified)
// 3-ring depth-2 counted-vmcnt + swizzled staging. Grid (8 n-fast, 64 m).
// ---------------------------------------------------------------------------
__global__ __launch_bounds__(256) void gemm_a16_c32(
    const bf16* __restrict__ A, const bf16* __restrict__ Bt,
    const float* __restrict__ bias, float* __restrict__ C)
{
  __shared__ bf16 S[24576];
  const int tid = threadIdx.x;
  const int wave = tid >> 6, lane = tid & 63;
  const int lr = lane & 15, quad = lane >> 4;
  const int n0 = blockIdx.x * 128;
  const int m0 = blockIdx.y * 128;
  const int wr = (wave >> 1) * 64, wc = (wave & 1) * 64;

  f32x4 acc[4][4];
#pragma unroll
  for (int i = 0; i < 4; i++)
#pragma unroll
    for (int j = 0; j < 4; j++)
#pragma unroll
      for (int e = 0; e < 4; e++) acc[i][j][e] = 0.f;

  const int srow = tid >> 2;
  const int sko = ((tid & 3) ^ ((srow >> 1) & 3)) * 8;
  const bf16* aPtr = A + (size_t)(m0 + srow) * 1024 + sko;
  const bf16* bPtr = Bt + (size_t)(n0 + srow) * 1024 + sko;

  int i0 = 0, i1 = 1, i2 = 2;
#pragma unroll
  for (int t = 0; t < 2; ++t) {
    bf16* nb = S + t * 8192;
    GLD(aPtr + t * 32,             nb + tid * 8);
    GLD(aPtr + 64 * 1024 + t * 32, nb + 2048 + tid * 8);
    GLD(bPtr + t * 32,             nb + 4096 + tid * 8);
    GLD(bPtr + 64 * 1024 + t * 32, nb + 6144 + tid * 8);
  }
  for (int it = 0; it < 30; ++it) {
    WAIT_BAR(4);
    const int k0 = (it + 2) * 32;
    bf16* nb = S + i2 * 8192;
    GLD(aPtr + k0,             nb + tid * 8);
    GLD(aPtr + 64 * 1024 + k0, nb + 2048 + tid * 8);
    GLD(bPtr + k0,             nb + 4096 + tid * 8);
    GLD(bPtr + 64 * 1024 + k0, nb + 6144 + tid * 8);
    compute128(S + i0 * 8192, wr, wc, lr, quad, acc);
    const int t = i0; i0 = i1; i1 = i2; i2 = t;
  }
  WAIT_BAR(4);
  compute128(S + i0 * 8192, wr, wc, lr, quad, acc);
  WAIT_BAR(0);
  compute128(S + i1 * 8192, wr, wc, lr, quad, acc);

  const int qd = quad * 4;
  float bv4[4];
#pragma unroll
  for (int in = 0; in < 4; in++) bv4[in] = bias[n0 + wc + in * 16 + lr];
#pragma unroll
  for (int im = 0; im < 4; im++) {
    const int row = m0 + wr + im * 16 + qd;
#pragma unroll
    for (int in = 0; in < 4; in++) {
      const int col = n0 + wc + in * 16 + lr;
#pragma unroll
      for (int i = 0; i < 4; i++)
        C[(size_t)(row + i) * 1024 + col] = acc[im][in][i] + bv4[in];
    }
  }
}

// ---------------------------------------------------------------------------
// Flash attention per (b,h). Q pre-scaled -> exp2 domain, no running max.
// ROUND-9 CHANGES (attn was never in top-5 => measured via dur total):
//  (1) mid __syncthreads REMOVED: sP is WAVE-PRIVATE (wave w writes rows
//      [wq,wq+32) and reads only those rows; within-wave LDS RAW is ordered
//      by compiler-inserted lgkmcnt). -16 block barriers, QK/PV phases of
//      different waves decouple -> setprio has role diversity to arbitrate.
//  (2) pa/pb hoisted out of the et loop (they are et-invariant; the setprio
//      fences blocked compiler hoisting): 16 -> 4 ds_read_b128 per tile.
// Grid (8 q FASTEST, 16 h, 8 b): panel-sharers in same residency window.
// O aliases Q (in-place).
// ---------------------------------------------------------------------------
__global__ __launch_bounds__(256) void attn_k(
    const bf16* Q, const bf16* __restrict__ Kh,
    const bf16* __restrict__ Vt, bf16* O)
{
  __shared__ bf16 sK[64 * 72];
  __shared__ bf16 sV[64 * 72];
  __shared__ bf16 sP[128 * 72];
  const int q0 = blockIdx.x * 128, h = blockIdx.y, b = blockIdx.z;
  const int tid = threadIdx.x, wave = tid >> 6, lane = tid & 63;
  const int lr = lane & 15, quad = lane >> 4, kq = quad * 8;
  const int wq = wave * 32;

  const bf16* Qb = Q + (size_t)(b * 1024 + q0) * 1024 + h * 64;
  const bf16* Kb = Kh + (size_t)(b * 1024) * 1024 + h * 64;
  const bf16* Vb = Vt + (size_t)(b * 16 + h) * 65536;

  bf16x8 qf[2][2];
#pragma unroll
  for (int rg = 0; rg < 2; rg++)
#pragma unroll
    for (int ks = 0; ks < 2; ks++)
      qf[rg][ks] = *(const bf16x8*)(Qb + (wq + rg * 16 + lr) * 1024 + ks * 32 + kq);

  f32x4 o[2][4];
  float rsum[2][4];
#pragma unroll
  for (int rg = 0; rg < 2; rg++) {
#pragma unroll
    for (int et = 0; et < 4; et++)
#pragma unroll
      for (int e = 0; e < 4; e++) o[rg][et][e] = 0.f;
#pragma unroll
    for (int i = 0; i < 4; i++) rsum[rg][i] = 0.f;
  }

  const int r = tid >> 3;
  const int c = (tid & 7) * 8;

  bf16x8 k1 = *(const bf16x8*)(Kb + (size_t)r * 1024 + c);
  bf16x8 k2 = *(const bf16x8*)(Kb + (size_t)(32 + r) * 1024 + c);
  bf16x8 v1 = *(const bf16x8*)(Vb + (size_t)r * 1024 + c);
  bf16x8 v2 = *(const bf16x8*)(Vb + (size_t)(32 + r) * 1024 + c);

  for (int kv0 = 0; kv0 < 1024; kv0 += 64) {
    __syncthreads();   // all waves done reading sK/sV of prev tile
    *(bf16x8*)(sK + r * 72 + c) = k1;
    *(bf16x8*)(sK + (32 + r) * 72 + c) = k2;
    *(bf16x8*)(sV + r * 72 + c) = v1;
    *(bf16x8*)(sV + (32 + r) * 72 + c) = v2;
    __syncthreads();   // stores visible to all
    if (kv0 + 64 < 1024) {
      k1 = *(const bf16x8*)(Kb + (size_t)(kv0 + 64 + r) * 1024 + c);
      k2 = *(const bf16x8*)(Kb + (size_t)(kv0 + 96 + r) * 1024 + c);
      v1 = *(const bf16x8*)(Vb + (size_t)r * 1024 + kv0 + 64 + c);
      v2 = *(const bf16x8*)(Vb + (size_t)(32 + r) * 1024 + kv0 + 64 + c);
    }

    f32x4 sc[2][4];
    __builtin_amdgcn_s_setprio(1);
#pragma unroll
    for (int nt = 0; nt < 4; nt++) {
      bf16x8 kf0 = *(const bf16x8*)(sK + (nt * 16 + lr) * 72 + kq);
      bf16x8 kf1 = *(const bf16x8*)(sK + (nt * 16 + lr) * 72 + 32 + kq);
#pragma unroll
      for (int rg = 0; rg < 2; rg++) {
        f32x4 z;
#pragma unroll
        for (int e = 0; e < 4; e++) z[e] = 0.f;
        z = mfma16(qf[rg][0], kf0, z);
        z = mfma16(qf[rg][1], kf1, z);
        sc[rg][nt] = z;
      }
    }
    __builtin_amdgcn_s_setprio(0);

#pragma unroll
    for (int rg = 0; rg < 2; rg++)
#pragma unroll
      for (int i = 0; i < 4; i++) {
        float p0 = fexp2(sc[rg][0][i]);
        float p1 = fexp2(sc[rg][1][i]);
        float p2 = fexp2(sc[rg][2][i]);
        float p3 = fexp2(sc[rg][3][i]);
        rsum[rg][i] += (p0 + p1) + (p2 + p3);
        const int prow = (wq + rg * 16 + quad * 4 + i) * 72;
        sP[prow + 0 * 16 + lr] = (bf16)p0;
        sP[prow + 1 * 16 + lr] = (bf16)p1;
        sP[prow + 2 * 16 + lr] = (bf16)p2;
        sP[prow + 3 * 16 + lr] = (bf16)p3;
      }
    // NO barrier: sP rows [wq,wq+32) are written and read by THIS wave only;
    // within-wave LDS ordering is guaranteed via lgkmcnt.

    bf16x8 pa[2], pb[2];
#pragma unroll
    for (int rg = 0; rg < 2; rg++) {
      pa[rg] = *(const bf16x8*)(sP + (wq + rg * 16 + lr) * 72 + kq);
      pb[rg] = *(const bf16x8*)(sP + (wq + rg * 16 + lr) * 72 + 32 + kq);
    }
    __builtin_amdgcn_s_setprio(1);
#pragma unroll
    for (int et = 0; et < 4; et++) {
      bf16x8 vf0 = *(const bf16x8*)(sV + (et * 16 + lr) * 72 + kq);
      bf16x8 vf1 = *(const bf16x8*)(sV + (et * 16 + lr) * 72 + 32 + kq);
#pragma unroll
      for (int rg = 0; rg < 2; rg++) {
        o[rg][et] = mfma16(pa[rg], vf0, o[rg][et]);
        o[rg][et] = mfma16(pb[rg], vf1, o[rg][et]);
      }
    }
    __builtin_amdgcn_s_setprio(0);
  }

#pragma unroll
  for (int rg = 0; rg < 2; rg++)
#pragma unroll
    for (int i = 0; i < 4; i++) {
      float rs = rsum[rg][i];
#pragma unroll
      for (int off = 1; off < 16; off <<= 1)
        rs += __shfl_xor(rs, off, 64);
      rsum[rg][i] = 1.f / rs;
    }

  bf16* Ob = O + (size_t)(b * 1024 + q0) * 1024 + h * 64;
#pragma unroll
  for (int rg = 0; rg < 2; rg++)
#pragma unroll
    for (int i = 0; i < 4; i++) {
      const int row = wq + rg * 16 + quad * 4 + i;
#pragma unroll
      for (int et = 0; et < 4; et++)
        Ob[row * 1024 + et * 16 + lr] = (bf16)(o[rg][et][i] * rsum[rg][i]);
    }
}

// ---------------------------------------------------------------------------
extern "C" void kernel_launch(void* const* d_in, const int* in_sizes, int n_in,
                              void* d_out, int out_size, void* d_ws, size_t ws_size,
                              hipStream_t stream)
{
  const float* q  = (const float*)d_in[0];
  const float* k  = (const float*)d_in[1];
  const float* v  = (const float*)d_in[2];
  const float* Wq = (const float*)d_in[3];
  const float* bq = (const float*)d_in[4];
  const float* Wk = (const float*)d_in[5];
  const float* bk = (const float*)d_in[6];
  const float* Wv = (const float*)d_in[7];
  const float* bv = (const float*)d_in[8];
  const float* Wo = (const float*)d_in[9];
  const float* bo = (const float*)d_in[10];
  float* out = (float*)d_out;
  bf16* ws = (bf16*)d_ws;

  const int MB = 1 << 20;
  bf16* WT  = ws;               // [3][1024][1024]
  bf16* qh  = ws + 3 * MB;      // [8192][1024]; attn writes O in-place here
  bf16* kh  = ws + 11 * MB;     // [8192][1024]
  bf16* vt  = ws + 19 * MB;     // [B*H][64 e][1024 s]
  bf16* WoT = ws + 27 * MB;     // [1024][1024]  (ws total 56 MB)
  bf16* qc  = (bf16*)d_out;             // d_out as scratch (dead before final GEMM)
  bf16* kc  = (bf16*)d_out + 8 * MB;

  const float cscale = 0.1803368801111601f;  // (1/8)*log2(e), folded into qh

  dim3 tb(32, 8);
  wtransA<<<dim3(32, 32, 12), tb, 0, stream>>>(Wq, Wk, Wv, Wo, WT, WoT,
                                               q, k, qc, kc);

  proj_qkv<<<dim3(8, 192), 256, 0, stream>>>(qc, kc, v, WT, bq, bk, bv,
                                             qh, kh, vt, cscale);

  attn_k<<<dim3(8, 16, 8), 256, 0, stream>>>(qh, kh, vt, qh);

  gemm_a16_c32<<<dim3(8, 64), 256, 0, stream>>>(qh, WoT, bo, out);
}